// Round 2
// baseline (2060.886 us; speedup 1.0000x reference)
//
#include <hip/hip_runtime.h>

#define NB 4
#define NPT 16384
#define NPOINT 1024
#define NSAMPLE 32

#define FPS_T 1024
#define FPS_PPT (NPT / FPS_T) /* 16 */
#define FPS_W (FPS_T / 64)    /* 16 waves */

#define BQ_WAVES 4
#define CAP 896 /* ball candidate cap; E[count]≈69, P(>200)~0 for uniform data */

// ---------------------------------------------------------------------------
// Kernel 1: farthest point sampling. One block per batch. Bit-exact with the
// JAX reference: d = ((dx*dx + dy*dy) + dz*dz), no FMA contraction, argmax
// with first-index tie-break.
// ---------------------------------------------------------------------------
__global__ __launch_bounds__(FPS_T) void fps_kernel(const float* __restrict__ pos,
                                                    float* __restrict__ new_pos) {
#pragma clang fp contract(off)
  const int b = blockIdx.x;
  const int tid = threadIdx.x;
  const int wid = tid >> 6;
  const int lane = tid & 63;
  const float* __restrict__ p = pos + (size_t)b * NPT * 3;

  float px[FPS_PPT], py[FPS_PPT], pz[FPS_PPT], md[FPS_PPT];
#pragma unroll
  for (int i = 0; i < FPS_PPT; ++i) {
    const int n = tid + i * FPS_T;
    px[i] = p[n * 3 + 0];
    py[i] = p[n * 3 + 1];
    pz[i] = p[n * 3 + 2];
    md[i] = 1e10f;
  }

  __shared__ unsigned long long red[2][FPS_W];

  float cx = p[0], cy = p[1], cz = p[2]; // far = 0 initially

  for (int j = 0; j < NPOINT; ++j) {
    if (tid == 0) {
      float* q = new_pos + ((size_t)b * NPOINT + j) * 3;
      q[0] = cx;
      q[1] = cy;
      q[2] = cz;
    }
    unsigned long long best = 0ull;
#pragma unroll
    for (int i = 0; i < FPS_PPT; ++i) {
      const float dx = px[i] - cx;
      const float dy = py[i] - cy;
      const float dz = pz[i] - cz;
      const float d = (dx * dx + dy * dy) + dz * dz; // >= 0, bits monotone
      const float m = fminf(md[i], d);
      md[i] = m;
      // max over (value, then smaller index wins): key = (bits(m)<<32) | ~idx
      const unsigned long long key =
          ((unsigned long long)__float_as_uint(m) << 32) |
          (unsigned)(~(tid + i * FPS_T));
      best = best < key ? key : best;
    }
    // wave argmax
#pragma unroll
    for (int off = 32; off > 0; off >>= 1) {
      const unsigned long long o = __shfl_xor(best, off, 64);
      best = best < o ? o : best;
    }
    if (lane == 0) red[j & 1][wid] = best;
    __syncthreads();
    // every thread reduces the 16 wave results (avoids a 2nd barrier+bcast)
    unsigned long long w = red[j & 1][0];
#pragma unroll
    for (int k = 1; k < FPS_W; ++k) {
      const unsigned long long o = red[j & 1][k];
      w = w < o ? o : w;
    }
    const int nf = (int)(~(unsigned)(w & 0xFFFFFFFFull));
    cx = p[nf * 3 + 0];
    cy = p[nf * 3 + 1];
    cz = p[nf * 3 + 2];
  }
}

// ---------------------------------------------------------------------------
// Kernel 2: fused ball query + grouping + shared MLP + max-pool.
// One wave per centroid, 4 waves per block. Selection = 32 smallest d2 within
// radius, ties by smaller index (== lax.top_k stable semantics). Only the SET
// matters for the max-pool, not the order.
// ---------------------------------------------------------------------------
__global__ __launch_bounds__(256) void bq_mlp_kernel(
    const float* __restrict__ pos, const float* __restrict__ x,
    const float* __restrict__ W1, const float* __restrict__ b1,
    const float* __restrict__ W2, const float* __restrict__ b2,
    const float* __restrict__ W3, const float* __restrict__ b3,
    const float* __restrict__ new_pos, float* __restrict__ out) {
#pragma clang fp contract(off)
  __shared__ __align__(16) float w1s[4 * 32];
  __shared__ __align__(16) float w2s[32 * 32];
  __shared__ __align__(16) float w3s[32 * 32];
  __shared__ float b1s[32], b2s[32], b3s[32];
  __shared__ unsigned long long list[BQ_WAVES][CAP];
  __shared__ int sel[BQ_WAVES][NSAMPLE];
  __shared__ unsigned cnt[BQ_WAVES];

  const int tid = threadIdx.x;
  const int wid = tid >> 6;
  const int lane = tid & 63;

  for (int i = tid; i < 128; i += 256) w1s[i] = W1[i];
  for (int i = tid; i < 1024; i += 256) {
    w2s[i] = W2[i];
    w3s[i] = W3[i];
  }
  if (tid < 32) {
    b1s[tid] = b1[tid];
    b2s[tid] = b2[tid];
    b3s[tid] = b3[tid];
  }
  if (lane == 0) cnt[wid] = 0u;
  __syncthreads();

  const int m_global = blockIdx.x * BQ_WAVES + wid; // 0..4095
  const int b = m_global >> 10;
  const float* __restrict__ p = pos + (size_t)b * NPT * 3;
  const float* __restrict__ xb = x + (size_t)b * NPT;

  const float cx = new_pos[(size_t)m_global * 3 + 0];
  const float cy = new_pos[(size_t)m_global * 3 + 1];
  const float cz = new_pos[(size_t)m_global * 3 + 2];
  const float snew = (cx * cx + cy * cy) + cz * cz;

  // ---- scan all points, collect in-ball candidates -------------------------
  for (int n = lane; n < NPT; n += 64) {
    const float px_ = p[n * 3 + 0];
    const float py_ = p[n * 3 + 1];
    const float pz_ = p[n * 3 + 2];
    const float spos = (px_ * px_ + py_ * py_) + pz_ * pz_;
    const float dot = (cx * px_ + cy * py_) + cz * pz_;
    const float d2 = (snew + spos) - 2.0f * dot; // reference op order
    if (d2 <= 0.01f) {                           // radius^2 in f32
      const unsigned u = __float_as_uint(d2);
      // order-preserving transform (d2 can be slightly negative)
      const unsigned key = (u & 0x80000000u) ? ~u : (u | 0x80000000u);
      const unsigned li = atomicAdd(&cnt[wid], 1u);
      if (li < CAP)
        list[wid][li] = ((unsigned long long)key << 32) | (unsigned)n;
    }
  }
  __syncthreads();

  int c = (int)cnt[wid];
  if (c > CAP) c = CAP;
  const int nsel = c < NSAMPLE ? c : NSAMPLE;

  // ---- rank-select the 32 smallest (d2, idx) -------------------------------
  for (int i = lane; i < c; i += 64) {
    const unsigned long long ki = list[wid][i];
    int rank = 0;
    for (int jj = 0; jj < c; ++jj) rank += (list[wid][jj] < ki) ? 1 : 0;
    if (rank < NSAMPLE) sel[wid][rank] = (int)(unsigned)(ki & 0xFFFFFFFFull);
  }
  __syncthreads();

  // ---- MLP per selected sample (lanes 0..nsel-1), then max-pool ------------
  const bool active = (lane < nsel);
  const int n = sel[wid][active ? lane : 0]; // nsel >= 1 always (self in ball)

  const float gpx = p[n * 3 + 0];
  const float gpy = p[n * 3 + 1];
  const float gpz = p[n * 3 + 2];
  const float gxv = xb[n];

  const float h0 = gpx - cx, h1i = gpy - cy, h2i = gpz - cz, h3i = gxv;

  float h1[32];
#pragma unroll
  for (int o = 0; o < 32; ++o) {
    float a = b1s[o];
    a += h0 * w1s[0 * 32 + o];
    a += h1i * w1s[1 * 32 + o];
    a += h2i * w1s[2 * 32 + o];
    a += h3i * w1s[3 * 32 + o];
    h1[o] = fmaxf(a, 0.0f);
  }

  float acc[32];
#pragma unroll
  for (int o = 0; o < 32; ++o) acc[o] = b2s[o];
  for (int k = 0; k < 32; ++k) {
    const float hk = h1[k];
    const float4* row = (const float4*)&w2s[k * 32];
#pragma unroll
    for (int q = 0; q < 8; ++q) {
      const float4 ww = row[q];
      acc[4 * q + 0] += hk * ww.x;
      acc[4 * q + 1] += hk * ww.y;
      acc[4 * q + 2] += hk * ww.z;
      acc[4 * q + 3] += hk * ww.w;
    }
  }
#pragma unroll
  for (int o = 0; o < 32; ++o) h1[o] = fmaxf(acc[o], 0.0f);

#pragma unroll
  for (int o = 0; o < 32; ++o) acc[o] = b3s[o];
  for (int k = 0; k < 32; ++k) {
    const float hk = h1[k];
    const float4* row = (const float4*)&w3s[k * 32];
#pragma unroll
    for (int q = 0; q < 8; ++q) {
      const float4 ww = row[q];
      acc[4 * q + 0] += hk * ww.x;
      acc[4 * q + 1] += hk * ww.y;
      acc[4 * q + 2] += hk * ww.z;
      acc[4 * q + 3] += hk * ww.w;
    }
  }
#pragma unroll
  for (int o = 0; o < 32; ++o)
    acc[o] = active ? fmaxf(acc[o], 0.0f) : -INFINITY;

  // max-pool across the 32 sample lanes (lanes 32..63 are all -inf; masks
  // <=16 keep the two 32-lane halves independent, lane 0 gets the result)
#pragma unroll
  for (int mask = 1; mask <= 16; mask <<= 1) {
#pragma unroll
    for (int o = 0; o < 32; ++o)
      acc[o] = fmaxf(acc[o], __shfl_xor(acc[o], mask, 64));
  }

  if (lane == 0) {
    float4* o4 = (float4*)(out + (size_t)m_global * 32);
#pragma unroll
    for (int q = 0; q < 8; ++q)
      o4[q] = make_float4(acc[4 * q + 0], acc[4 * q + 1], acc[4 * q + 2],
                          acc[4 * q + 3]);
  }
}

// ---------------------------------------------------------------------------
extern "C" void kernel_launch(void* const* d_in, const int* in_sizes, int n_in,
                              void* d_out, int out_size, void* d_ws,
                              size_t ws_size, hipStream_t stream) {
  const float* pos = (const float*)d_in[0];
  const float* x = (const float*)d_in[1];
  const float* W1 = (const float*)d_in[2];
  const float* b1 = (const float*)d_in[3];
  const float* W2 = (const float*)d_in[4];
  const float* b2 = (const float*)d_in[5];
  const float* W3 = (const float*)d_in[6];
  const float* b3 = (const float*)d_in[7];
  float* out = (float*)d_out;
  float* new_pos = (float*)d_ws; // NB*NPOINT*3 floats = 48 KiB

  fps_kernel<<<NB, FPS_T, 0, stream>>>(pos, new_pos);
  bq_mlp_kernel<<<(NB * NPOINT) / BQ_WAVES, 256, 0, stream>>>(
      pos, x, W1, b1, W2, b2, W3, b3, new_pos, out);
}

// Round 6
// 1906.275 us; speedup vs baseline: 1.0811x; 1.0811x over previous
//
#include <hip/hip_runtime.h>

#define NB 4
#define NPT 16384
#define NPOINT 1024
#define NSAMPLE 32

#define FPS_T 512
#define FPS_PPT (NPT / FPS_T) /* 32 points per thread, idx = tid*32 + i */

#define BQ_WAVES 4
#define CAP 896

// ---------------------------------------------------------------------------
// Kernel 1: farthest point sampling. One block (512 thr / 8 waves) per batch.
// Bit-exact with the JAX reference: d = ((dx*dx+dy*dy)+dz*dz), contract off,
// argmax with first-index (lowest global idx) tie-break.
//
// Layout is i-major (idx = tid*32+i) so that on value ties the lowest LANE is
// the lowest global index -> 32-bit value-only wave reduce + ballot resolve.
// Cross-wave reduce: one LDS atomicMax on a u64 (valbits<<32 | ~idx) key,
// triple-buffered so the clear is always two barriers away from last use.
// ---------------------------------------------------------------------------
__global__ __launch_bounds__(FPS_T, 2) void fps_kernel(
    const float* __restrict__ pos, float* __restrict__ new_pos) {
#pragma clang fp contract(off)
  const int b = blockIdx.x;
  const int tid = threadIdx.x;
  const int wid = tid >> 6;
  const int lane = tid & 63;
  const float* __restrict__ p = pos + (size_t)b * NPT * 3;

  float px[FPS_PPT], py[FPS_PPT], pz[FPS_PPT], md[FPS_PPT];

  // load 32 consecutive points (384B) per thread via float4, static unpack
  {
    const float4* pf4 = (const float4*)(p + (size_t)tid * (FPS_PPT * 3));
#pragma unroll
    for (int k = 0; k < FPS_PPT / 4; ++k) { // 8 groups of (3 float4 = 4 pts)
      const float4 a = pf4[3 * k + 0];
      const float4 bq = pf4[3 * k + 1];
      const float4 c = pf4[3 * k + 2];
      px[4 * k + 0] = a.x; py[4 * k + 0] = a.y; pz[4 * k + 0] = a.z;
      px[4 * k + 1] = a.w; py[4 * k + 1] = bq.x; pz[4 * k + 1] = bq.y;
      px[4 * k + 2] = bq.z; py[4 * k + 2] = bq.w; pz[4 * k + 2] = c.x;
      px[4 * k + 3] = c.y; py[4 * k + 3] = c.z; pz[4 * k + 3] = c.w;
    }
#pragma unroll
    for (int i = 0; i < FPS_PPT; ++i) md[i] = 1e10f;
  }

  __shared__ unsigned long long red[3];
  if (tid < 3) red[tid] = 0ull;
  __syncthreads();

  float cx = p[0], cy = p[1], cz = p[2]; // far = 0 initially

  for (int j = 0; j < NPOINT; ++j) {
    if (tid == 0) {
      float* q = new_pos + ((size_t)b * NPOINT + j) * 3;
      q[0] = cx;
      q[1] = cy;
      q[2] = cz;
    }
    // ---- distance pass + per-thread argmax (first-i on ties) ---------------
    float bm = -1.0f;
    int bi = 0;
#pragma unroll
    for (int i = 0; i < FPS_PPT; ++i) {
      const float dx = px[i] - cx;
      const float dy = py[i] - cy;
      const float dz = pz[i] - cz;
      const float d = (dx * dx + dy * dy) + dz * dz;
      const float m = fminf(md[i], d);
      md[i] = m;
      if (m > bm) { // strict: keeps lowest i on exact ties
        bm = m;
        bi = i;
      }
    }
    // ---- in-wave value max + lowest-lane resolve ---------------------------
    float wm = bm;
#pragma unroll
    for (int off = 1; off < 64; off <<= 1)
      wm = fmaxf(wm, __shfl_xor(wm, off, 64));
    const unsigned long long tied = __ballot(bm == wm);
    const int wl = __ffsll((long long)tied) - 1; // lowest tied lane = lowest idx
    const int wbi = __shfl(bi, wl, 64);
    const int widx = ((wid << 6) + wl) * FPS_PPT + wbi;
    // ---- cross-wave: one LDS u64 atomicMax ---------------------------------
    if (lane == 0) {
      const unsigned long long key =
          ((unsigned long long)__float_as_uint(wm) << 32) |
          (unsigned)(~widx);
      atomicMax(&red[j % 3], key);
    }
    __syncthreads();
    const unsigned long long w = red[j % 3];
    if (tid == 0) red[(j + 2) % 3] = 0ull; // 2 barriers from any prior use
    const int nf = (int)(~(unsigned)w);
    cx = p[nf * 3 + 0];
    cy = p[nf * 3 + 1];
    cz = p[nf * 3 + 2];
  }
}

// ---------------------------------------------------------------------------
// Kernel 2: fused ball query + grouping + shared MLP + max-pool.
// One wave per centroid, 4 waves per block. Selection = 32 smallest d2 within
// radius, ties by smaller index (== lax.top_k stable semantics).
// ---------------------------------------------------------------------------
__global__ __launch_bounds__(256) void bq_mlp_kernel(
    const float* __restrict__ pos, const float* __restrict__ x,
    const float* __restrict__ W1, const float* __restrict__ b1,
    const float* __restrict__ W2, const float* __restrict__ b2,
    const float* __restrict__ W3, const float* __restrict__ b3,
    const float* __restrict__ new_pos, float* __restrict__ out) {
#pragma clang fp contract(off)
  __shared__ __align__(16) float w1s[4 * 32];
  __shared__ __align__(16) float w2s[32 * 32];
  __shared__ __align__(16) float w3s[32 * 32];
  __shared__ float b1s[32], b2s[32], b3s[32];
  __shared__ unsigned long long list[BQ_WAVES][CAP];
  __shared__ int sel[BQ_WAVES][NSAMPLE];
  __shared__ unsigned cnt[BQ_WAVES];

  const int tid = threadIdx.x;
  const int wid = tid >> 6;
  const int lane = tid & 63;

  for (int i = tid; i < 128; i += 256) w1s[i] = W1[i];
  for (int i = tid; i < 1024; i += 256) {
    w2s[i] = W2[i];
    w3s[i] = W3[i];
  }
  if (tid < 32) {
    b1s[tid] = b1[tid];
    b2s[tid] = b2[tid];
    b3s[tid] = b3[tid];
  }
  if (lane == 0) cnt[wid] = 0u;
  __syncthreads();

  const int m_global = blockIdx.x * BQ_WAVES + wid; // 0..4095
  const int b = m_global >> 10;
  const float* __restrict__ p = pos + (size_t)b * NPT * 3;
  const float* __restrict__ xb = x + (size_t)b * NPT;

  const float cx = new_pos[(size_t)m_global * 3 + 0];
  const float cy = new_pos[(size_t)m_global * 3 + 1];
  const float cz = new_pos[(size_t)m_global * 3 + 2];
  const float snew = (cx * cx + cy * cy) + cz * cz;

  // ---- scan all points (4 per lane per iter, 48B/lane coalesced) -----------
  for (int it = 0; it < NPT / 256; ++it) {
    const int n0 = it * 256 + lane * 4;
    const float4* pf4 = (const float4*)(p + (size_t)n0 * 3);
    const float4 a = pf4[0];
    const float4 bq = pf4[1];
    const float4 c = pf4[2];
    float qx[4], qy[4], qz[4];
    qx[0] = a.x;  qy[0] = a.y;  qz[0] = a.z;
    qx[1] = a.w;  qy[1] = bq.x; qz[1] = bq.y;
    qx[2] = bq.z; qy[2] = bq.w; qz[2] = c.x;
    qx[3] = c.y;  qy[3] = c.z;  qz[3] = c.w;
#pragma unroll
    for (int t = 0; t < 4; ++t) {
      const float spos = (qx[t] * qx[t] + qy[t] * qy[t]) + qz[t] * qz[t];
      const float dot = (cx * qx[t] + cy * qy[t]) + cz * qz[t];
      const float d2 = (snew + spos) - 2.0f * dot; // reference op order
      if (d2 <= 0.01f) {
        const unsigned u = __float_as_uint(d2);
        const unsigned key = (u & 0x80000000u) ? ~u : (u | 0x80000000u);
        const unsigned li = atomicAdd(&cnt[wid], 1u);
        if (li < CAP)
          list[wid][li] = ((unsigned long long)key << 32) | (unsigned)(n0 + t);
      }
    }
  }
  __syncthreads();

  int c = (int)cnt[wid];
  if (c > CAP) c = CAP;
  const int nsel = c < NSAMPLE ? c : NSAMPLE;

  // ---- rank-select the 32 smallest (d2, idx) -------------------------------
  for (int i = lane; i < c; i += 64) {
    const unsigned long long ki = list[wid][i];
    int rank = 0;
    for (int jj = 0; jj < c; ++jj) rank += (list[wid][jj] < ki) ? 1 : 0;
    if (rank < NSAMPLE) sel[wid][rank] = (int)(unsigned)(ki & 0xFFFFFFFFull);
  }
  __syncthreads();

  // ---- MLP per selected sample (lanes 0..nsel-1), then max-pool ------------
  const bool active = (lane < nsel);
  const int n = sel[wid][active ? lane : 0];

  const float gpx = p[n * 3 + 0];
  const float gpy = p[n * 3 + 1];
  const float gpz = p[n * 3 + 2];
  const float gxv = xb[n];

  const float h0 = gpx - cx, h1i = gpy - cy, h2i = gpz - cz, h3i = gxv;

  float h1[32];
#pragma unroll
  for (int o = 0; o < 32; ++o) {
    float a = b1s[o];
    a += h0 * w1s[0 * 32 + o];
    a += h1i * w1s[1 * 32 + o];
    a += h2i * w1s[2 * 32 + o];
    a += h3i * w1s[3 * 32 + o];
    h1[o] = fmaxf(a, 0.0f);
  }

  float acc[32];
#pragma unroll
  for (int o = 0; o < 32; ++o) acc[o] = b2s[o];
  for (int k = 0; k < 32; ++k) {
    const float hk = h1[k];
    const float4* row = (const float4*)&w2s[k * 32];
#pragma unroll
    for (int q = 0; q < 8; ++q) {
      const float4 ww = row[q];
      acc[4 * q + 0] += hk * ww.x;
      acc[4 * q + 1] += hk * ww.y;
      acc[4 * q + 2] += hk * ww.z;
      acc[4 * q + 3] += hk * ww.w;
    }
  }
#pragma unroll
  for (int o = 0; o < 32; ++o) h1[o] = fmaxf(acc[o], 0.0f);

#pragma unroll
  for (int o = 0; o < 32; ++o) acc[o] = b3s[o];
  for (int k = 0; k < 32; ++k) {
    const float hk = h1[k];
    const float4* row = (const float4*)&w3s[k * 32];
#pragma unroll
    for (int q = 0; q < 8; ++q) {
      const float4 ww = row[q];
      acc[4 * q + 0] += hk * ww.x;
      acc[4 * q + 1] += hk * ww.y;
      acc[4 * q + 2] += hk * ww.z;
      acc[4 * q + 3] += hk * ww.w;
    }
  }
#pragma unroll
  for (int o = 0; o < 32; ++o)
    acc[o] = active ? fmaxf(acc[o], 0.0f) : -INFINITY;

#pragma unroll
  for (int mask = 1; mask <= 16; mask <<= 1) {
#pragma unroll
    for (int o = 0; o < 32; ++o)
      acc[o] = fmaxf(acc[o], __shfl_xor(acc[o], mask, 64));
  }

  if (lane == 0) {
    float4* o4 = (float4*)(out + (size_t)m_global * 32);
#pragma unroll
    for (int q = 0; q < 8; ++q)
      o4[q] = make_float4(acc[4 * q + 0], acc[4 * q + 1], acc[4 * q + 2],
                          acc[4 * q + 3]);
  }
}

// ---------------------------------------------------------------------------
extern "C" void kernel_launch(void* const* d_in, const int* in_sizes, int n_in,
                              void* d_out, int out_size, void* d_ws,
                              size_t ws_size, hipStream_t stream) {
  const float* pos = (const float*)d_in[0];
  const float* x = (const float*)d_in[1];
  const float* W1 = (const float*)d_in[2];
  const float* b1 = (const float*)d_in[3];
  const float* W2 = (const float*)d_in[4];
  const float* b2 = (const float*)d_in[5];
  const float* W3 = (const float*)d_in[6];
  const float* b3 = (const float*)d_in[7];
  float* out = (float*)d_out;
  float* new_pos = (float*)d_ws; // NB*NPOINT*3 floats = 48 KiB

  fps_kernel<<<NB, FPS_T, 0, stream>>>(pos, new_pos);
  bq_mlp_kernel<<<(NB * NPOINT) / BQ_WAVES, 256, 0, stream>>>(
      pos, x, W1, b1, W2, b2, W3, b3, new_pos, out);
}